// Round 2
// baseline (285.321 us; speedup 1.0000x reference)
//
#include <hip/hip_runtime.h>
#include <math.h>

#define NDIRS 64
#define NBIN 65
#define THREADS 128
#define NBLK 2048
#define DCHUNK 8
#define NCHUNK 8            // 8*8 = 64 dirs
#define NCOPY 8             // 16-lane sub-wave hist replicas (2 waves x 4)
#define HSIZE (DCHUNK*NBIN) // 520
#define LDSF (NCOPY*HSIZE)  // 4160 floats = 16.6 KB
#define RROWS 16
#define CONS_STRIDE 16
#define ROW_FLOATS (NDIRS*NBIN) // 4160

static constexpr float INV = 0.28867513459481287f; // 1/(2*sqrt(3))

__global__ void wect_setup(const float* __restrict__ dirs, float* __restrict__ cons) {
  int k = threadIdx.x;
  if (k < NDIRS) {
    float d0 = dirs[3*k], d1 = dirs[3*k+1], d2 = dirs[3*k+2];
    float q0 = fmaxf(d0,0.f)*INV, q1 = fmaxf(d1,0.f)*INV, q2 = fmaxf(d2,0.f)*INV;
    float* c = cons + k*CONS_STRIDE;
    c[0]=d0*INV; c[1]=d1*INV; c[2]=d2*INV; c[3]=q0;   // float4 A
    c[4]=q1; c[5]=q2; c[6]=q1+q2; c[7]=q0+q2;         // float4 B
    c[8]=q0+q1; c[9]=q0+q1+q2; c[10]=0.f; c[11]=0.f;  // float4 C
    c[12]=0.f; c[13]=0.f; c[14]=0.f; c[15]=0.f;
  }
}

__global__ __launch_bounds__(THREADS) void wect_hist(
    const float* __restrict__ x, const float* __restrict__ cons,
    float* __restrict__ accum) {
  __shared__ float hist[LDSF];
  const int tid = threadIdx.x;
  const int b = blockIdx.x;
  // Diagonal mapping: block = 16 diagonal (i,j) rows x 8 strided l positions.
  // Guarantees a wave's 64 simultaneous cells spread >=4 bins for ANY direction
  // (i, j, and l all vary across lanes) while loads stay line-local.
  const int bs = b >> 3, bo = b & 7;
  const int rp = tid & 15, lp = tid >> 4;          // lp in [0,8) = hist copy id
  const int row = ((bs*16 + rp)*65) & 4095;        // stride-65 bijection mod 4096
  const int i = row >> 6, j = row & 63, l = lp*8 + bo;

  const float* p = x + row*64 + l;
  const int dL = (l<63)?1:0, dJ = (j<63)?64:0, dI = (i<63)?4096:0;
  const bool iv = dI!=0, jv = dJ!=0, lv = dL!=0;
  const float x000=p[0],      x001=p[dL],      x010=p[dJ],      x011=p[dJ+dL];
  const float x100=p[dI],     x101=p[dI+dL],   x110=p[dI+dJ],   x111=p[dI+dJ+dL];
  const float e0m = fmaxf(x000,x100), e1m = fmaxf(x000,x010), e2m = fmaxf(x000,x001);
  const float s12 = fmaxf(fmaxf(e1m,x001),x011);
  const float s02 = fmaxf(fmaxf(e0m,x001),x101);
  const float s01 = fmaxf(fmaxf(e0m,x010),x110);
  const float cc  = fmaxf(fmaxf(s01,fmaxf(x001,x101)),fmaxf(x011,x111));
  // signed, boundary-masked aggregates; order matches q-order in cons
  const float v1 = iv ? -e0m : 0.f;
  const float v2 = jv ? -e1m : 0.f;
  const float v3 = lv ? -e2m : 0.f;
  const float v4 = (jv&&lv) ? s12 : 0.f;
  const float v5 = (iv&&lv) ? s02 : 0.f;
  const float v6 = (iv&&jv) ? s01 : 0.f;
  const float v7 = (iv&&jv&&lv) ? -cc : 0.f;
  const float T = x000 + v1+v2+v3+v4+v5+v6+v7;
  const float fi = (float)i, fj = (float)j, fl = (float)l;
  float* hbase = hist + lp * HSIZE;
  const int arow = (b & (RROWS-1)) * ROW_FLOATS;

  for (int ch = 0; ch < NCHUNK; ++ch) {
    for (int idx = tid; idx < LDSF; idx += THREADS) hist[idx] = 0.f;
    __syncthreads();
    #pragma unroll
    for (int dd = 0; dd < DCHUNK; ++dd) {
      const int dir = ch*DCHUNK + dd;               // wave-uniform -> s_load
      const float4* C4 = (const float4*)(cons + dir*CONS_STRIDE);
      const float4 cA = C4[0];  // e0,e1,e2,q0
      const float4 cB = C4[1];  // q1,q2,q12,q02
      const float4 cC = C4[2];  // q01,q012,-,-
      const float u  = fl*cA.z + (fi*cA.x + fj*cA.y);
      const float bf = ceilf(u);
      const float fr = bf - u;                      // in [0,1)
      int ib = (int)bf + 32;
      ib = min(max(ib,0),64);
      float S = 0.f;                                // items spilling to ib+1
      S += (cA.w > fr) ? v1 : 0.f;
      S += (cB.x > fr) ? v2 : 0.f;
      S += (cB.y > fr) ? v3 : 0.f;
      S += (cB.z > fr) ? v4 : 0.f;
      S += (cB.w > fr) ? v5 : 0.f;
      S += (cC.x > fr) ? v6 : 0.f;
      S += (cC.y > fr) ? v7 : 0.f;
      float* hrow = hbase + dd*NBIN;
      atomicAdd(&hrow[ib], T - S);
      atomicAdd(&hrow[min(ib+1,64)], S);
    }
    __syncthreads();
    for (int idx = tid; idx < HSIZE; idx += THREADS) {
      float s = 0.f;
      #pragma unroll
      for (int c = 0; c < NCOPY; ++c) s += hist[c*HSIZE + idx];
      unsafeAtomicAdd(&accum[arow + ch*HSIZE + idx], s);
    }
    __syncthreads();
  }
}

__global__ __launch_bounds__(128) void wect_scan(
    const float* __restrict__ accum, float* __restrict__ out) {
  __shared__ float s[NBIN];
  const int k = blockIdx.x, t = threadIdx.x;
  if (t < NBIN) {
    float v = 0.f;
    #pragma unroll
    for (int r = 0; r < RROWS; ++r) v += accum[r*ROW_FLOATS + k*NBIN + t];
    s[t] = v;
  }
  __syncthreads();
  for (int off = 1; off < NBIN; off <<= 1) {
    float a = 0.f;
    if (t < NBIN && t >= off) a = s[t-off];
    __syncthreads();
    if (t < NBIN && t >= off) s[t] += a;
    __syncthreads();
  }
  if (t < NBIN) out[k*NBIN + t] = s[t];
}

extern "C" void kernel_launch(void* const* d_in, const int* in_sizes, int n_in,
                              void* d_out, int out_size, void* d_ws, size_t ws_size,
                              hipStream_t stream) {
  const float* x = (const float*)d_in[0];
  const float* dirs = (const float*)d_in[1];
  float* out = (float*)d_out;
  float* cons = (float*)d_ws;                      // 1024 floats (4 KB)
  float* accum = cons + NDIRS*CONS_STRIDE;         // 16*4160 floats (266 KB)

  hipMemsetAsync(accum, 0, RROWS*ROW_FLOATS*sizeof(float), stream);
  wect_setup<<<1, 64, 0, stream>>>(dirs, cons);
  wect_hist<<<NBLK, THREADS, 0, stream>>>(x, cons, accum);
  wect_scan<<<NDIRS, 128, 0, stream>>>(accum, out);
}

// Round 3
// 241.029 us; speedup vs baseline: 1.1838x; 1.1838x over previous
//
#include <hip/hip_runtime.h>
#include <math.h>

#define NDIRS 64
#define NBIN 65
#define HISTF (NDIRS*NBIN + 1)   // +1 spill-guard slot (dir 63, bin 65)
#define THREADS 512
#define WPB (THREADS/64)         // 8 waves per block
#define NBLK 512                 // 512*8 = 4096 strips = 64*64 (i,j) rows
#define RROWS 64
#define ROWF (NDIRS*NBIN)        // 4160

static constexpr float INV = 0.28867513459481287f; // 1/(2*sqrt(3))

__device__ __forceinline__ float rdlane(float v, int t) {
  return __int_as_float(__builtin_amdgcn_readlane(__float_as_int(v), t));
}

__global__ __launch_bounds__(THREADS) void wect_hist(
    const float* __restrict__ x, const float* __restrict__ dirs,
    float* __restrict__ accum) {
  __shared__ float hist[HISTF];
  const int tid = threadIdx.x;
  for (int idx = tid; idx < HISTF; idx += THREADS) hist[idx] = 0.f;
  __syncthreads();

  const int lane = tid & 63;
  const int wid  = tid >> 6;

  // lane = DIRECTION for the main loop: per-lane constants (pre-scaled by 1/dh)
  const float D0 = dirs[3*lane+0] * INV;
  const float D1 = dirs[3*lane+1] * INV;
  const float D2 = dirs[3*lane+2] * INV;
  const float Q1 = fmaxf(D0, 0.f);               // q0
  const float Q2 = fmaxf(D1, 0.f);               // q1
  const float Q3 = fmaxf(D2, 0.f);               // q2
  const float Q4 = Q2 + Q3;                      // q12
  const float Q5 = Q1 + Q3;                      // q02
  const float Q6 = Q1 + Q2;                      // q01
  const float Q7 = Q1 + Q2 + Q3;                 // q012

  // lane = CELL (l) for the load phase: one l-row of 64 cells per wave
  const int strip = blockIdx.x * WPB + wid;      // [0, 4096)
  const int i = strip >> 6, j = strip & 63;
  const int l = lane;
  const float* p = x + (strip << 6) + l;
  const int dL = (l < 63) ? 1 : 0;
  const int dJ = (j < 63) ? 64 : 0;
  const int dI = (i < 63) ? 4096 : 0;
  const bool iv = dI != 0, jv = dJ != 0, lv = dL != 0;

  const float x000 = p[0],       x001 = p[dL];
  const float x010 = p[dJ],      x011 = p[dJ+dL];
  const float x100 = p[dI],      x101 = p[dI+dL];
  const float x110 = p[dI+dJ],   x111 = p[dI+dJ+dL];

  const float e0m = fmaxf(x000, x100);
  const float e1m = fmaxf(x000, x010);
  const float e2m = fmaxf(x000, x001);
  const float s12 = fmaxf(fmaxf(e1m, x001), x011);
  const float s02 = fmaxf(fmaxf(e0m, x001), x101);
  const float s01 = fmaxf(fmaxf(e0m, x010), x110);
  const float cc  = fmaxf(fmaxf(s01, fmaxf(x001, x101)), fmaxf(x011, x111));

  // signed, validity-masked aggregates (order matches Q1..Q7)
  const float v1 = iv ? -e0m : 0.f;
  const float v2 = jv ? -e1m : 0.f;
  const float v3 = lv ? -e2m : 0.f;
  const float v4 = (jv && lv) ? s12 : 0.f;
  const float v5 = (iv && lv) ? s02 : 0.f;
  const float v6 = (iv && jv) ? s01 : 0.f;
  const float v7 = (iv && jv && lv) ? -cc : 0.f;
  const float T  = x000 + v1+v2+v3+v4+v5+v6+v7;

  const float u0 = (float)i * D0 + (float)j * D1;  // per-lane(dir), strip-fixed

  #pragma unroll 16
  for (int t = 0; t < 64; ++t) {
    // broadcast cell t's aggregates (wave-uniform -> SGPRs)
    const float bT = rdlane(T,  t);
    const float b1 = rdlane(v1, t);
    const float b2 = rdlane(v2, t);
    const float b3 = rdlane(v3, t);
    const float b4 = rdlane(v4, t);
    const float b5 = rdlane(v5, t);
    const float b6 = rdlane(v6, t);
    const float b7 = rdlane(v7, t);
    // each lane bins cell t under ITS OWN direction
    const float u  = fmaf((float)t, D2, u0);
    const float bf = ceilf(u);
    const float fr = bf - u;                 // [0,1)
    const int   ib = (int)bf + 32;           // provably in [1,64]
    float S = 0.f;                           // portion spilling to ib+1
    S += (Q1 > fr) ? b1 : 0.f;
    S += (Q2 > fr) ? b2 : 0.f;
    S += (Q3 > fr) ? b3 : 0.f;
    S += (Q4 > fr) ? b4 : 0.f;
    S += (Q5 > fr) ? b5 : 0.f;
    S += (Q6 > fr) ? b6 : 0.f;
    S += (Q7 > fr) ? b7 : 0.f;
    const int a = lane * NBIN + ib;          // distinct row per lane: conflict-free
    atomicAdd(&hist[a],     bT - S);
    atomicAdd(&hist[a + 1], S);              // if ib==64, S==0 -> harmless
  }

  __syncthreads();
  const int arow = (blockIdx.x & (RROWS-1)) * ROWF;
  for (int idx = tid; idx < ROWF; idx += THREADS)
    unsafeAtomicAdd(&accum[arow + idx], hist[idx]);
}

__global__ __launch_bounds__(128) void wect_scan(
    const float* __restrict__ accum, float* __restrict__ out) {
  __shared__ float s[NBIN];
  const int k = blockIdx.x, t = threadIdx.x;
  if (t < NBIN) {
    float v = 0.f;
    #pragma unroll
    for (int r = 0; r < RROWS; ++r) v += accum[r*ROWF + k*NBIN + t];
    s[t] = v;
  }
  __syncthreads();
  for (int off = 1; off < NBIN; off <<= 1) {
    float a = 0.f;
    if (t < NBIN && t >= off) a = s[t-off];
    __syncthreads();
    if (t < NBIN && t >= off) s[t] += a;
    __syncthreads();
  }
  if (t < NBIN) out[k*NBIN + t] = s[t];
}

extern "C" void kernel_launch(void* const* d_in, const int* in_sizes, int n_in,
                              void* d_out, int out_size, void* d_ws, size_t ws_size,
                              hipStream_t stream) {
  const float* x = (const float*)d_in[0];
  const float* dirs = (const float*)d_in[1];
  float* out = (float*)d_out;
  float* accum = (float*)d_ws;   // 64*4160 floats = 1,064,960 B

  hipMemsetAsync(accum, 0, RROWS*ROWF*sizeof(float), stream);
  wect_hist<<<NBLK, THREADS, 0, stream>>>(x, dirs, accum);
  wect_scan<<<NDIRS, 128, 0, stream>>>(accum, out);
}

// Round 4
// 104.015 us; speedup vs baseline: 2.7431x; 2.3173x over previous
//
#include <hip/hip_runtime.h>
#include <math.h>

#define NDIRS 64
#define NBIN 65
#define HSTRIDE 66               // 65 bins + 1 discard slot per row
#define HIST1 (NDIRS*HSTRIDE)    // 4224 floats per wave-private hist
#define THREADS 256
#define WPB 4                    // waves per block
#define SPW 2                    // strips per wave
#define NBLK 512                 // 512*4*2 = 4096 strips = all (i,j)
#define RROWS 64
#define ROWF (NDIRS*NBIN)        // 4160

static constexpr float INV = 0.28867513459481287f; // 1/(2*sqrt(3))

__device__ __forceinline__ float rdlane(float v, int t) {
  return __int_as_float(__builtin_amdgcn_readlane(__float_as_int(v), t));
}

__global__ __launch_bounds__(THREADS) void wect_hist(
    const float* __restrict__ x, const float* __restrict__ dirs,
    float* __restrict__ accum) {
  __shared__ float hist[WPB * HIST1];          // 67,584 B -> 2 blocks/CU
  const int tid = threadIdx.x;
  const int lane = tid & 63;
  const int wid  = tid >> 6;

  float4* h4 = (float4*)hist;
  for (int idx = tid; idx < WPB * HIST1 / 4; idx += THREADS)
    h4[idx] = make_float4(0.f, 0.f, 0.f, 0.f);
  __syncthreads();

  // lane = DIRECTION constants (pre-scaled by 1/dh)
  const float D0 = dirs[3*lane+0] * INV;
  const float D1 = dirs[3*lane+1] * INV;
  const float D2 = dirs[3*lane+2] * INV;
  const float Q1 = fmaxf(D0, 0.f);
  const float Q2 = fmaxf(D1, 0.f);
  const float Q3 = fmaxf(D2, 0.f);
  const float Q4 = Q2 + Q3;
  const float Q5 = Q1 + Q3;
  const float Q6 = Q1 + Q2;
  const float Q7 = Q1 + Q2 + Q3;

  float* __restrict__ myrow = hist + wid * HIST1 + lane * HSTRIDE;

  for (int s = 0; s < SPW; ++s) {
    const int strip = (blockIdx.x * WPB + wid) * SPW + s;   // [0,4096)
    const int i = strip >> 6, j = strip & 63;
    const int l = lane;                         // lane = CELL for load phase
    const float* p = x + (strip << 6) + l;
    const int dL = (l < 63) ? 1 : 0;
    const int dJ = (j < 63) ? 64 : 0;
    const int dI = (i < 63) ? 4096 : 0;
    const bool iv = dI != 0, jv = dJ != 0, lv = dL != 0;

    const float x000 = p[0],       x001 = p[dL];
    const float x010 = p[dJ],      x011 = p[dJ+dL];
    const float x100 = p[dI],      x101 = p[dI+dL];
    const float x110 = p[dI+dJ],   x111 = p[dI+dJ+dL];

    const float e0m = fmaxf(x000, x100);
    const float e1m = fmaxf(x000, x010);
    const float e2m = fmaxf(x000, x001);
    const float s12 = fmaxf(fmaxf(e1m, x001), x011);
    const float s02 = fmaxf(fmaxf(e0m, x001), x101);
    const float s01 = fmaxf(fmaxf(e0m, x010), x110);
    const float cc  = fmaxf(fmaxf(s01, fmaxf(x001, x101)), fmaxf(x011, x111));

    const float v1 = iv ? -e0m : 0.f;
    const float v2 = jv ? -e1m : 0.f;
    const float v3 = lv ? -e2m : 0.f;
    const float v4 = (jv && lv) ? s12 : 0.f;
    const float v5 = (iv && lv) ? s02 : 0.f;
    const float v6 = (iv && jv) ? s01 : 0.f;
    const float v7 = (iv && jv && lv) ? -cc : 0.f;
    const float T  = x000 + v1+v2+v3+v4+v5+v6+v7;

    const float u0 = (float)i * D0 + (float)j * D1;   // per-lane(dir)

    #pragma unroll 8
    for (int t = 0; t < 64; ++t) {
      const float bT = rdlane(T,  t);
      const float b1 = rdlane(v1, t);
      const float b2 = rdlane(v2, t);
      const float b3 = rdlane(v3, t);
      const float b4 = rdlane(v4, t);
      const float b5 = rdlane(v5, t);
      const float b6 = rdlane(v6, t);
      const float b7 = rdlane(v7, t);
      const float u  = fmaf((float)t, D2, u0);
      const float bf = ceilf(u);
      const float fr = bf - u;                 // [0,1)
      const int   ib = (int)bf + 32;           // in [0,64]
      float S = 0.f;
      S += (Q1 > fr) ? b1 : 0.f;
      S += (Q2 > fr) ? b2 : 0.f;
      S += (Q3 > fr) ? b3 : 0.f;
      S += (Q4 > fr) ? b4 : 0.f;
      S += (Q5 > fr) ? b5 : 0.f;
      S += (Q6 > fr) ? b6 : 0.f;
      S += (Q7 > fr) ? b7 : 0.f;
      // non-atomic RMW: lane-private row, same-wave DS ops are in-order
      float* a = myrow + ib;
      const float r0 = a[0], r1 = a[1];
      a[0] = r0 + (bT - S);
      a[1] = r1 + S;                           // ib==64 -> discard slot 65
    }
  }

  __syncthreads();
  // sum the 4 wave-private copies, flush to one of 64 accum rows
  const int arow = (blockIdx.x & (RROWS - 1)) * ROWF;
  for (int z = tid; z < ROWF; z += THREADS) {
    const int r = z / NBIN, c = z - r * NBIN;
    const int li = r * HSTRIDE + c;
    const float sacc = hist[li] + hist[HIST1 + li]
                     + hist[2*HIST1 + li] + hist[3*HIST1 + li];
    unsafeAtomicAdd(&accum[arow + z], sacc);
  }
}

__global__ __launch_bounds__(128) void wect_scan(
    const float* __restrict__ accum, float* __restrict__ out) {
  __shared__ float s[NBIN];
  const int k = blockIdx.x, t = threadIdx.x;
  if (t < NBIN) {
    float v = 0.f;
    #pragma unroll
    for (int r = 0; r < RROWS; ++r) v += accum[r*ROWF + k*NBIN + t];
    s[t] = v;
  }
  __syncthreads();
  for (int off = 1; off < NBIN; off <<= 1) {
    float a = 0.f;
    if (t < NBIN && t >= off) a = s[t-off];
    __syncthreads();
    if (t < NBIN && t >= off) s[t] += a;
    __syncthreads();
  }
  if (t < NBIN) out[k*NBIN + t] = s[t];
}

extern "C" void kernel_launch(void* const* d_in, const int* in_sizes, int n_in,
                              void* d_out, int out_size, void* d_ws, size_t ws_size,
                              hipStream_t stream) {
  const float* x = (const float*)d_in[0];
  const float* dirs = (const float*)d_in[1];
  float* out = (float*)d_out;
  float* accum = (float*)d_ws;   // 64*4160 floats = 1,064,960 B

  hipMemsetAsync(accum, 0, RROWS*ROWF*sizeof(float), stream);
  wect_hist<<<NBLK, THREADS, 0, stream>>>(x, dirs, accum);
  wect_scan<<<NDIRS, 128, 0, stream>>>(accum, out);
}